// Round 7
// baseline (907.419 us; speedup 1.0000x reference)
//
#include <hip/hip_runtime.h>
#include <hip/hip_bf16.h>

#define NTOK 8192
#define DM 1024
#define DFF 4096
#define NE 8
#define TPAD 72  // max 256-row tiles: 16384/256 + 8 partials, padded (even)

typedef __attribute__((ext_vector_type(8))) short bf16x8;
typedef __attribute__((ext_vector_type(4))) float f32x4;

__device__ __forceinline__ ushort f2bf(float f) {
  __hip_bfloat16 h = __float2bfloat16(f);
  return *reinterpret_cast<ushort*>(&h);
}

// ---------- W [R][C] fp32 -> Wt [C][R] bf16, per expert (blockIdx.z) ----------
__global__ void transpose_cvt(const float* __restrict__ in, ushort* __restrict__ out,
                              int R, int C) {
  __shared__ float t[64][65];
  const float* inp = in + (size_t)blockIdx.z * R * C;
  ushort* op = out + (size_t)blockIdx.z * R * C;
  int c0 = blockIdx.x * 64, r0 = blockIdx.y * 64;
  int tid = threadIdx.x;
#pragma unroll
  for (int it = 0; it < 4; ++it) {
    int r = it * 16 + (tid >> 4);
    int c = (tid & 15) * 4;
    float4 v = *reinterpret_cast<const float4*>(inp + (size_t)(r0 + r) * C + c0 + c);
    t[r][c] = v.x; t[r][c + 1] = v.y; t[r][c + 2] = v.z; t[r][c + 3] = v.w;
  }
  __syncthreads();
  int c = tid >> 2, rc = (tid & 3) * 16;
  union { ushort us[16]; uint4 q[2]; } u;
#pragma unroll
  for (int i = 0; i < 16; ++i) u.us[i] = f2bf(t[rc + i][c]);
  uint4* dst = reinterpret_cast<uint4*>(op + (size_t)(c0 + c) * R + r0 + rc);
  dst[0] = u.q[0];
  dst[1] = u.q[1];
}

// ---------------- router (fused x->bf16 conversion) ----------------
__global__ void router_kernel(const float* __restrict__ x, const float* __restrict__ router,
                              int* __restrict__ cnt, int* __restrict__ list,
                              float* __restrict__ wa, ushort* __restrict__ xb) {
  __shared__ float rl[DM * NE];  // 32 KB
  int tid = threadIdx.x;
  for (int i = tid; i < DM * NE / 4; i += 256)
    reinterpret_cast<float4*>(rl)[i] = reinterpret_cast<const float4*>(router)[i];
  __syncthreads();
  int wave = tid >> 6, lane = tid & 63;
  int tok0 = blockIdx.x * 32 + wave * 8;
  for (int tI = 0; tI < 8; ++tI) {
    int tok = tok0 + tI;
    float acc[NE];
#pragma unroll
    for (int e2 = 0; e2 < NE; ++e2) acc[e2] = 0.f;
    const float4* xr = reinterpret_cast<const float4*>(x + (size_t)tok * DM);
    ushort xo[16];
#pragma unroll
    for (int c = 0; c < 4; ++c) {
      float4 v = xr[lane * 4 + c];
      int d = lane * 16 + c * 4;
      const float* vv = reinterpret_cast<const float*>(&v);
#pragma unroll
      for (int q = 0; q < 4; ++q) {
        float xv = vv[q];
        xo[c * 4 + q] = f2bf(xv);
#pragma unroll
        for (int e2 = 0; e2 < NE; ++e2) acc[e2] += xv * rl[(d + q) * NE + e2];
      }
    }
    *reinterpret_cast<uint4*>(xb + (size_t)tok * DM + lane * 16) =
        *reinterpret_cast<const uint4*>(&xo[0]);
    *reinterpret_cast<uint4*>(xb + (size_t)tok * DM + lane * 16 + 8) =
        *reinterpret_cast<const uint4*>(&xo[8]);
    for (int off = 32; off > 0; off >>= 1) {
#pragma unroll
      for (int e2 = 0; e2 < NE; ++e2) acc[e2] += __shfl_xor(acc[e2], off, 64);
    }
    if (lane == 0) {
      int i0 = 0; float v0 = acc[0];
#pragma unroll
      for (int e2 = 1; e2 < NE; ++e2) { if (acc[e2] > v0) { v0 = acc[e2]; i0 = e2; } }
      int i1 = -1; float v1 = -3.4e38f;
#pragma unroll
      for (int e2 = 0; e2 < NE; ++e2) { if (e2 != i0 && acc[e2] > v1) { v1 = acc[e2]; i1 = e2; } }
      float e1 = expf(v1 - v0);
      float w0 = 1.f / (1.f + e1);
      float w1 = e1 / (1.f + e1);
      int s0 = atomicAdd(&cnt[i0], 1);
      list[i0 * NTOK + s0] = tok * 2;
      wa[tok * 2] = w0;
      int s1 = atomicAdd(&cnt[i1], 1);
      list[i1 * NTOK + s1] = tok * 2 + 1;
      wa[tok * 2 + 1] = w1;
    }
  }
}

// ---------------- tile table: flat tile -> (expert, tTile), BM=256 ----------------
__global__ void build_tiles(const int* __restrict__ cnt, unsigned* __restrict__ table) {
  if (threadIdx.x == 0) {
    int t = 0;
    for (int e = 0; e < NE; ++e) {
      int nt = (cnt[e] + 255) >> 8;
      for (int i = 0; i < nt; ++i) table[t++] = ((unsigned)e << 16) | (unsigned)i;
    }
    for (; t < TPAD; ++t) table[t] = 0xFFFFFFFFu;
  }
}

// ---------------- helpers ----------------
__device__ __forceinline__ void gl_lds16(unsigned long long g, void* s) {
  __builtin_amdgcn_global_load_lds(
      (const __attribute__((address_space(1))) unsigned int*)g,
      (__attribute__((address_space(3))) unsigned int*)s, 16, 0, 0);
}

#define WAITV(N) asm volatile("s_waitcnt vmcnt(" #N ")" ::: "memory")

__device__ __forceinline__ void BARRIER() {
  asm volatile("" ::: "memory");
  __builtin_amdgcn_s_barrier();
  asm volatile("" ::: "memory");
}

// ---------------- 8-phase-style sparse expert GEMM (m201 port) ----------------
// 256x256 tile, BK=64, 8 waves (2M x 4N), 2-slot dbuf (128 KB LDS), 4 phases per
// K-step: each = {8 ds_read_b128 quadrant + 1 chunk gl_lds of next tile + 16 MFMA
// with setprio}. Waves FREE-RUN through phases (only lgkm deps, auto-inserted);
// 2 barriers + 1 counted vmcnt per K-step; boundary pre-stages tile t+2's chunk 0
// before vmcnt(2) => never drains in steady state (T4). Zero-conflict XOR swizzle
// on source+read (R3-R6 PMC-verified). XCD-banded grid, sequential K.
template <int PASS>
__launch_bounds__(512, 2)
__global__ void moe_gemm(const ushort* __restrict__ Abase,
                         const ushort* __restrict__ Wt,
                         const int* __restrict__ cnt,
                         const int* __restrict__ list,
                         const unsigned* __restrict__ table,
                         const float* __restrict__ wa,
                         ushort* __restrict__ Hbuf,
                         float* __restrict__ out) {
  constexpr int K = (PASS == 1) ? DM : DFF;
  constexpr int NK = K / 64;
  constexpr int NB = (PASS == 1) ? DFF : DM;
  constexpr int SLOT = 256 * 128;  // 32 KB per operand slot

  const int bid = blockIdx.x;
  const int xcd = bid & 7;
  const int j = bid >> 3;
  int t, nTile;
  if (PASS == 1) { t = j % TPAD; nTile = (j / TPAD) * 8 + xcd; }
  else           { t = (j << 1) + (xcd >> 2); nTile = xcd & 3; }
  unsigned td = table[t];
  if (td == 0xFFFFFFFFu) return;  // uniform exit before any barrier
  const int e = td >> 16;
  const int tTile = td & 0xFFFF;
  const int n = cnt[e];

  __shared__ __attribute__((aligned(16))) char As[2 * SLOT];
  __shared__ __attribute__((aligned(16))) char Bs[2 * SLOT];
  __shared__ int aL[256];
  __shared__ unsigned long long pL[256];

  const int tid = threadIdx.x;
  if (tid < 256) {
    int slot = tTile * 256 + tid;
    int sl = (slot < n) ? slot : (n - 1);
    int a = list[e * NTOK + sl];
    aL[tid] = (slot < n) ? a : -1;
    size_t row = (PASS == 1) ? (size_t)(a >> 1) : (size_t)a;
    pL[tid] = (unsigned long long)(Abase + row * K);  // byte address of A row
  }
  __syncthreads();

  // staging: 512 threads x 16B = 8 KB per issue = 64-row chunk; 4 chunks/operand.
  // swizzle folded into SOURCE column; LDS dest linear (rule 21).
  const char* WtE = (const char*)(Wt + (size_t)e * NB * K);
  const int sr = tid >> 3;        // 0..63 (row within chunk)
  const int sc = (tid & 7) * 16;  // base byte col
  const unsigned swc = (unsigned)(sc ^ ((sr & 7) << 4));
  unsigned long long sAc[4], sBc[4];
  unsigned dD[4];
#pragma unroll
  for (int c = 0; c < 4; ++c) {
    int row = c * 64 + sr;
    sAc[c] = pL[row] + swc;
    sBc[c] = (unsigned long long)WtE + (size_t)(nTile * 256 + row) * (K * 2) + swc;
    dD[c] = (unsigned)(row * 128 + sc);
  }

  auto STAGE_CHUNK = [&](int slot, int c, int tile) {
    const unsigned ko = (unsigned)tile << 7;  // tile*128 bytes along K
    gl_lds16(sAc[c] + ko, As + slot * SLOT + dD[c]);
    gl_lds16(sBc[c] + ko, Bs + slot * SLOT + dD[c]);
  };

  const int wv = tid >> 6, lane = tid & 63;
  const int wm = wv >> 2, wn = wv & 3;  // 2M x 4N
  const unsigned lxor = (unsigned)((lane & 7) << 4);

  f32x4 acc[8][4];
#pragma unroll
  for (int m = 0; m < 8; ++m)
#pragma unroll
    for (int nn = 0; nn < 4; ++nn) acc[m][nn] = (f32x4){0.f, 0.f, 0.f, 0.f};

  bf16x8 bq[4];  // B-frag cache, persists across the two mh-phases of a kk

  // phase: quadrant (mh, kk); optionally refresh B cache; optionally stage chunk stC
  auto PHASE = [&](int cs, int ns, int mh, int kk, bool readB, int stC, bool hn, int kt) {
    const char* a_ = As + cs * SLOT;
    const char* b_ = Bs + cs * SLOT;
    const unsigned kb = (unsigned)(kk * 64 + (lane >> 4) * 16);
    if (readB) {
#pragma unroll
      for (int nn = 0; nn < 4; ++nn) {
        int row = wn * 64 + nn * 16 + (lane & 15);
        bq[nn] = *reinterpret_cast<const bf16x8*>(b_ + row * 128 + (kb ^ lxor));
      }
    }
    bf16x8 af[4];
#pragma unroll
    for (int m = 0; m < 4; ++m) {
      int row = wm * 128 + mh * 64 + m * 16 + (lane & 15);
      af[m] = *reinterpret_cast<const bf16x8*>(a_ + row * 128 + (kb ^ lxor));
    }
    if (hn && stC > 0) STAGE_CHUNK(ns, stC, kt + 1);
    __builtin_amdgcn_s_setprio(1);
#pragma unroll
    for (int m = 0; m < 4; ++m)
#pragma unroll
      for (int nn = 0; nn < 4; ++nn)
        acc[mh * 4 + m][nn] =
            __builtin_amdgcn_mfma_f32_16x16x32_bf16(af[m], bq[nn], acc[mh * 4 + m][nn], 0, 0, 0);
    __builtin_amdgcn_s_setprio(0);
  };

  // prologue: tile0 fully, tile1 chunk0; wait for tile0 (2 in flight), barrier
#pragma unroll
  for (int c = 0; c < 4; ++c) STAGE_CHUNK(0, c, 0);
  STAGE_CHUNK(1, 0, 1);
  WAITV(2);
  BARRIER();

  for (int kt = 0; kt < NK; ++kt) {
    const int cs = kt & 1, ns = cs ^ 1;
    const bool hn = (kt + 1 < NK);
    PHASE(cs, ns, 0, 0, true,  1, hn, kt);   // read B(kk0); stage chunk1 of t+1
    PHASE(cs, ns, 1, 0, false, 2, hn, kt);   // reuse B;     stage chunk2
    PHASE(cs, ns, 0, 1, true,  3, hn, kt);   // read B(kk1); stage chunk3
    PHASE(cs, ns, 1, 1, false, 0, false, kt); // reuse B;    no stage
    BARRIER();  // all waves done reading slot cs
    if (kt + 2 < NK) {
      STAGE_CHUNK(cs, 0, kt + 2);  // pre-stage t+2 chunk0 into freed slot
      WAITV(2);                    // t+1 fully landed; t+2's 2 loads in flight
      BARRIER();
    } else if (hn) {
      WAITV(0);                    // last boundary: drain once
      BARRIER();
    }
  }

  // epilogue — C/D layout: col = lane&15, row = (lane>>4)*4 + j
#pragma unroll
  for (int m = 0; m < 8; ++m) {
#pragma unroll
    for (int jr = 0; jr < 4; ++jr) {
      int lr = wm * 128 + m * 16 + (lane >> 4) * 4 + jr;
      int a = aL[lr];
      if (a < 0) continue;
      if (PASS == 1) {
        ushort* hrow = Hbuf + (size_t)a * DFF + nTile * 256 + wn * 64 + (lane & 15);
#pragma unroll
        for (int nn = 0; nn < 4; ++nn) {
          float v = acc[m][nn][jr];
          hrow[nn * 16] = f2bf(v / (1.f + expf(-v)));  // swish
        }
      } else {
        float w = wa[a];
        int tok = a >> 1;
        float* orow = out + (size_t)tok * DM + nTile * 256 + wn * 64 + (lane & 15);
#pragma unroll
        for (int nn = 0; nn < 4; ++nn)
          atomicAdd(&orow[nn * 16], w * acc[m][nn][jr]);  // exactly 2 contributions
      }
    }
  }
}

extern "C" void kernel_launch(void* const* d_in, const int* in_sizes, int n_in,
                              void* d_out, int out_size, void* d_ws, size_t ws_size,
                              hipStream_t stream) {
  const float* x = (const float*)d_in[0];
  const float* router = (const float*)d_in[1];
  const float* W1 = (const float*)d_in[2];
  const float* W2 = (const float*)d_in[3];
  float* out = (float*)d_out;
  char* ws = (char*)d_ws;

  size_t off = 0;
  ushort* Xb = (ushort*)(ws + off); off += (size_t)NTOK * DM * 2;          // 16 MB
  ushort* Wt1 = (ushort*)(ws + off); off += (size_t)NE * DM * DFF * 2;     // 64 MB
  ushort* Wt2 = (ushort*)(ws + off); off += (size_t)NE * DM * DFF * 2;     // 64 MB
  ushort* H   = (ushort*)(ws + off); off += (size_t)NTOK * 2 * DFF * 2;    // 128 MB
  int* cnt  = (int*)(ws + off); off += 256;
  int* list = (int*)(ws + off); off += (size_t)NE * NTOK * 4;
  float* wa = (float*)(ws + off); off += (size_t)NTOK * 2 * 4;
  unsigned* table = (unsigned*)(ws + off); off += TPAD * 4;

  hipMemsetAsync(out, 0, (size_t)NTOK * DM * sizeof(float), stream);
  hipMemsetAsync(cnt, 0, NE * sizeof(int), stream);

  transpose_cvt<<<dim3(DFF / 64, DM / 64, NE), 256, 0, stream>>>(W1, Wt1, DM, DFF);
  transpose_cvt<<<dim3(DM / 64, DFF / 64, NE), 256, 0, stream>>>(W2, Wt2, DFF, DM);
  router_kernel<<<NTOK / 32, 256, 0, stream>>>(x, router, cnt, list, wa, Xb);
  build_tiles<<<1, 64, 0, stream>>>(cnt, table);

  // pass1: 16 nTiles (2 chunks/XCD), tile-fastest within XCD; pass2: 4 nTiles (XCD pairs)
  moe_gemm<1><<<8 * 2 * TPAD, 512, 0, stream>>>(Xb, Wt1, cnt, list, table, wa, H, out);
  moe_gemm<2><<<8 * (TPAD / 2), 512, 0, stream>>>(H, Wt2, cnt, list, table, wa, H, out);
}

// Round 8
// 698.834 us; speedup vs baseline: 1.2985x; 1.2985x over previous
//
#include <hip/hip_runtime.h>
#include <hip/hip_bf16.h>

#define NTOK 8192
#define DM 1024
#define DFF 4096
#define NE 8
#define MAXT 136  // max 128-row tiles: 16384/128 + 8 partials

typedef __attribute__((ext_vector_type(8))) short bf16x8;
typedef __attribute__((ext_vector_type(4))) float f32x4;

__device__ __forceinline__ ushort f2bf(float f) {
  __hip_bfloat16 h = __float2bfloat16(f);
  return *reinterpret_cast<ushort*>(&h);
}

// ---------- W [R][C] fp32 -> Wt [C][R] bf16, per expert (blockIdx.z) ----------
__global__ void transpose_cvt(const float* __restrict__ in, ushort* __restrict__ out,
                              int R, int C) {
  __shared__ float t[64][65];
  const float* inp = in + (size_t)blockIdx.z * R * C;
  ushort* op = out + (size_t)blockIdx.z * R * C;
  int c0 = blockIdx.x * 64, r0 = blockIdx.y * 64;
  int tid = threadIdx.x;
#pragma unroll
  for (int it = 0; it < 4; ++it) {
    int r = it * 16 + (tid >> 4);
    int c = (tid & 15) * 4;
    float4 v = *reinterpret_cast<const float4*>(inp + (size_t)(r0 + r) * C + c0 + c);
    t[r][c] = v.x; t[r][c + 1] = v.y; t[r][c + 2] = v.z; t[r][c + 3] = v.w;
  }
  __syncthreads();
  int c = tid >> 2, rc = (tid & 3) * 16;
  union { ushort us[16]; uint4 q[2]; } u;
#pragma unroll
  for (int i = 0; i < 16; ++i) u.us[i] = f2bf(t[rc + i][c]);
  uint4* dst = reinterpret_cast<uint4*>(op + (size_t)(c0 + c) * R + r0 + rc);
  dst[0] = u.q[0];
  dst[1] = u.q[1];
}

// ---------------- router (fused x->bf16 conversion) ----------------
__global__ void router_kernel(const float* __restrict__ x, const float* __restrict__ router,
                              int* __restrict__ cnt, int* __restrict__ list,
                              float* __restrict__ wa, ushort* __restrict__ xb) {
  __shared__ float rl[DM * NE];  // 32 KB
  int tid = threadIdx.x;
  for (int i = tid; i < DM * NE / 4; i += 256)
    reinterpret_cast<float4*>(rl)[i] = reinterpret_cast<const float4*>(router)[i];
  __syncthreads();
  int wave = tid >> 6, lane = tid & 63;
  int tok0 = blockIdx.x * 32 + wave * 8;
  for (int tI = 0; tI < 8; ++tI) {
    int tok = tok0 + tI;
    float acc[NE];
#pragma unroll
    for (int e2 = 0; e2 < NE; ++e2) acc[e2] = 0.f;
    const float4* xr = reinterpret_cast<const float4*>(x + (size_t)tok * DM);
    ushort xo[16];
#pragma unroll
    for (int c = 0; c < 4; ++c) {
      float4 v = xr[lane * 4 + c];
      int d = lane * 16 + c * 4;
      const float* vv = reinterpret_cast<const float*>(&v);
#pragma unroll
      for (int q = 0; q < 4; ++q) {
        float xv = vv[q];
        xo[c * 4 + q] = f2bf(xv);
#pragma unroll
        for (int e2 = 0; e2 < NE; ++e2) acc[e2] += xv * rl[(d + q) * NE + e2];
      }
    }
    *reinterpret_cast<uint4*>(xb + (size_t)tok * DM + lane * 16) =
        *reinterpret_cast<const uint4*>(&xo[0]);
    *reinterpret_cast<uint4*>(xb + (size_t)tok * DM + lane * 16 + 8) =
        *reinterpret_cast<const uint4*>(&xo[8]);
    for (int off = 32; off > 0; off >>= 1) {
#pragma unroll
      for (int e2 = 0; e2 < NE; ++e2) acc[e2] += __shfl_xor(acc[e2], off, 64);
    }
    if (lane == 0) {
      int i0 = 0; float v0 = acc[0];
#pragma unroll
      for (int e2 = 1; e2 < NE; ++e2) { if (acc[e2] > v0) { v0 = acc[e2]; i0 = e2; } }
      int i1 = -1; float v1 = -3.4e38f;
#pragma unroll
      for (int e2 = 0; e2 < NE; ++e2) { if (e2 != i0 && acc[e2] > v1) { v1 = acc[e2]; i1 = e2; } }
      float e1 = expf(v1 - v0);
      float w0 = 1.f / (1.f + e1);
      float w1 = e1 / (1.f + e1);
      int s0 = atomicAdd(&cnt[i0], 1);
      list[i0 * NTOK + s0] = tok * 2;
      wa[tok * 2] = w0;
      int s1 = atomicAdd(&cnt[i1], 1);
      list[i1 * NTOK + s1] = tok * 2 + 1;
      wa[tok * 2 + 1] = w1;
    }
  }
}

// ---------------- tile table: flat tile -> (expert, tTile), BM=128 ----------------
__global__ void build_tiles(const int* __restrict__ cnt, unsigned* __restrict__ table) {
  if (threadIdx.x == 0) {
    int t = 0;
    for (int e = 0; e < NE; ++e) {
      int nt = (cnt[e] + 127) >> 7;
      for (int i = 0; i < nt; ++i) table[t++] = ((unsigned)e << 16) | (unsigned)i;
    }
    for (; t < MAXT; ++t) table[t] = 0xFFFFFFFFu;
  }
}

// ---------------- helpers ----------------
__device__ __forceinline__ void gl_lds16(unsigned long long g, void* s) {
  __builtin_amdgcn_global_load_lds(
      (const __attribute__((address_space(1))) unsigned int*)g,
      (__attribute__((address_space(3))) unsigned int*)s, 16, 0, 0);
}

#define WAITV0() asm volatile("s_waitcnt vmcnt(0)" ::: "memory")

__device__ __forceinline__ void BARRIER() {
  asm volatile("" ::: "memory");
  __builtin_amdgcn_s_barrier();
  asm volatile("" ::: "memory");
}

// ---------------- sparse expert GEMM: occupancy-first single-buffer ----------------
// 128x128 tile, BK=64 (128B XOR-swizzled rows, zero-conflict PMC-verified), 4 waves,
// single-buffered LDS (34 KB) -> 4 blocks/CU. Cross-block wave overlap (m114) hides
// stage latency; requires surplus block generations -> pass2 K-split. SEQUENTIAL K
// (R6's rotation inflated FETCH 303->849 MB; removed). XCD-banded 1-D grid,
// tile-fastest within XCD => resident blocks share B panels (L2) + A via L3.
template <int PASS, int CPX, int KSPLIT>
__launch_bounds__(256, 4)
__global__ void moe_gemm(const ushort* __restrict__ Abase,
                         const ushort* __restrict__ Wt,
                         const int* __restrict__ cnt,
                         const int* __restrict__ list,
                         const unsigned* __restrict__ table,
                         const float* __restrict__ wa,
                         ushort* __restrict__ Hbuf,
                         float* __restrict__ out) {
  constexpr int K = (PASS == 1) ? DM : DFF;
  constexpr int KCH = K / KSPLIT;
  constexpr int NK = KCH / 64;
  constexpr int NB = (PASS == 1) ? DFF : DM;

  const int bid = blockIdx.x;
  const int xcd = bid & 7;
  const int j = bid >> 3;
  const int c = j / MAXT;
  const int t = j - c * MAXT;
  unsigned td = table[t];
  if (td == 0xFFFFFFFFu) return;  // uniform exit before any barrier
  const int e = td >> 16;
  const int tTile = td & 0xFFFF;
  const int n = cnt[e];
  int nTile, kc;
  if (KSPLIT == 1) { nTile = xcd * CPX + c; kc = 0; }
  else             { nTile = xcd; kc = c; }
  const int kbase = kc * KCH;

  __shared__ __attribute__((aligned(16))) char As[128 * 128];  // 16 KB
  __shared__ __attribute__((aligned(16))) char Bs[128 * 128];  // 16 KB
  __shared__ int aL[128];
  __shared__ unsigned long long pL[128];

  const int tid = threadIdx.x;
  if (tid < 128) {
    int slot = tTile * 128 + tid;
    int sl = (slot < n) ? slot : (n - 1);
    int a = list[e * NTOK + sl];
    aL[tid] = (slot < n) ? a : -1;
    size_t row = (PASS == 1) ? (size_t)(a >> 1) : (size_t)a;
    pL[tid] = (unsigned long long)Abase + ((size_t)row * K + kbase) * 2;  // byte addr
  }
  __syncthreads();

  // staging: 8 threads/row x 16B, 4 row-groups of 32 per operand.
  // swizzle folded into SOURCE column; LDS dest linear (rule 21).
  const char* WtE = (const char*)(Wt + (size_t)e * NB * K);
  const int sr = tid >> 3;        // 0..31
  const int sc = (tid & 7) * 16;  // base byte col
  unsigned long long sA0[4], sB0[4];
  unsigned dst[4];
#pragma unroll
  for (int jj = 0; jj < 4; ++jj) {
    int row = jj * 32 + sr;
    unsigned swc = (unsigned)(sc ^ ((row & 7) << 4));
    sA0[jj] = pL[row] + swc;
    sB0[jj] = (unsigned long long)WtE + ((size_t)(nTile * 128 + row) * K + kbase) * 2 + swc;
    dst[jj] = (unsigned)(row * 128 + sc);
  }

  const int wv = tid >> 6, lane = tid & 63;
  const int r0 = (wv >> 1) * 64, c0 = (wv & 1) * 64;

  f32x4 acc[4][4];
#pragma unroll
  for (int m = 0; m < 4; ++m)
#pragma unroll
    for (int nn = 0; nn < 4; ++nn) acc[m][nn] = (f32x4){0.f, 0.f, 0.f, 0.f};

  for (int kt = 0; kt < NK; ++kt) {
    const unsigned kbyt = (unsigned)kt << 7;  // kt*128 bytes along K
#pragma unroll
    for (int jj = 0; jj < 4; ++jj) {
      gl_lds16(sA0[jj] + kbyt, As + dst[jj]);
      gl_lds16(sB0[jj] + kbyt, Bs + dst[jj]);
    }
    WAITV0();
    BARRIER();
#pragma unroll
    for (int kk = 0; kk < 2; ++kk) {
      const int kb = kk * 64 + (lane >> 4) * 16;
      bf16x8 af[4], bfr[4];
#pragma unroll
      for (int m = 0; m < 4; ++m) {
        int row = r0 + m * 16 + (lane & 15);
        af[m] = *reinterpret_cast<const bf16x8*>(As + row * 128 + (kb ^ ((row & 7) << 4)));
      }
#pragma unroll
      for (int nn = 0; nn < 4; ++nn) {
        int row = c0 + nn * 16 + (lane & 15);
        bfr[nn] = *reinterpret_cast<const bf16x8*>(Bs + row * 128 + (kb ^ ((row & 7) << 4)));
      }
      __builtin_amdgcn_s_setprio(1);
#pragma unroll
      for (int m = 0; m < 4; ++m)
#pragma unroll
        for (int nn = 0; nn < 4; ++nn)
          acc[m][nn] = __builtin_amdgcn_mfma_f32_16x16x32_bf16(af[m], bfr[nn], acc[m][nn], 0, 0, 0);
      __builtin_amdgcn_s_setprio(0);
    }
    BARRIER();  // WAR: all waves done reading before next stage overwrites
  }

  // epilogue — C/D layout: col = lane&15, row = (lane>>4)*4 + j
#pragma unroll
  for (int m = 0; m < 4; ++m) {
#pragma unroll
    for (int jr = 0; jr < 4; ++jr) {
      int lr = r0 + m * 16 + (lane >> 4) * 4 + jr;
      int a = aL[lr];
      if (a < 0) continue;
      if (PASS == 1) {
        ushort* hrow = Hbuf + (size_t)a * DFF + nTile * 128 + c0 + (lane & 15);
#pragma unroll
        for (int nn = 0; nn < 4; ++nn) {
          float v = acc[m][nn][jr];
          hrow[nn * 16] = f2bf(v / (1.f + expf(-v)));  // swish
        }
      } else {
        float w = wa[a];
        int tok = a >> 1;
        float* orow = out + (size_t)tok * DM + nTile * 128 + c0 + (lane & 15);
#pragma unroll
        for (int nn = 0; nn < 4; ++nn)
          atomicAdd(&orow[nn * 16], w * acc[m][nn][jr]);  // 2 experts x KSPLIT adds
      }
    }
  }
}

extern "C" void kernel_launch(void* const* d_in, const int* in_sizes, int n_in,
                              void* d_out, int out_size, void* d_ws, size_t ws_size,
                              hipStream_t stream) {
  const float* x = (const float*)d_in[0];
  const float* router = (const float*)d_in[1];
  const float* W1 = (const float*)d_in[2];
  const float* W2 = (const float*)d_in[3];
  float* out = (float*)d_out;
  char* ws = (char*)d_ws;

  size_t off = 0;
  ushort* Xb = (ushort*)(ws + off); off += (size_t)NTOK * DM * 2;          // 16 MB
  ushort* Wt1 = (ushort*)(ws + off); off += (size_t)NE * DM * DFF * 2;     // 64 MB
  ushort* Wt2 = (ushort*)(ws + off); off += (size_t)NE * DM * DFF * 2;     // 64 MB
  ushort* H   = (ushort*)(ws + off); off += (size_t)NTOK * 2 * DFF * 2;    // 128 MB
  int* cnt  = (int*)(ws + off); off += 256;
  int* list = (int*)(ws + off); off += (size_t)NE * NTOK * 4;
  float* wa = (float*)(ws + off); off += (size_t)NTOK * 2 * 4;
  unsigned* table = (unsigned*)(ws + off); off += MAXT * 4;

  hipMemsetAsync(out, 0, (size_t)NTOK * DM * sizeof(float), stream);
  hipMemsetAsync(cnt, 0, NE * sizeof(int), stream);

  transpose_cvt<<<dim3(DFF / 64, DM / 64, NE), 256, 0, stream>>>(W1, Wt1, DM, DFF);
  transpose_cvt<<<dim3(DM / 64, DFF / 64, NE), 256, 0, stream>>>(W2, Wt2, DFF, DM);
  router_kernel<<<NTOK / 32, 256, 0, stream>>>(x, router, cnt, list, wa, Xb);
  build_tiles<<<1, 64, 0, stream>>>(cnt, table);

  // pass1: 32 nTiles -> 4 chunks/XCD, full K. grid 4352 (~4.25 generations)
  moe_gemm<1, 4, 1><<<8 * 4 * MAXT, 256, 0, stream>>>(Xb, Wt1, cnt, list, table, wa, H, out);
  // pass2: 8 nTiles x K-split 2 -> 2 chunks/XCD. grid 2176 (~2.1 generations)
  moe_gemm<2, 2, 2><<<8 * 2 * MAXT, 256, 0, stream>>>(H, Wt2, cnt, list, table, wa, H, out);
}

// Round 9
// 675.192 us; speedup vs baseline: 1.3439x; 1.0350x over previous
//
#include <hip/hip_runtime.h>
#include <hip/hip_bf16.h>

#define NTOK 8192
#define DM 1024
#define DFF 4096
#define NE 8
#define MAXT 136  // max 128-row tiles: 16384/128 + 8 partials

typedef __attribute__((ext_vector_type(8))) short bf16x8;
typedef __attribute__((ext_vector_type(4))) float f32x4;

__device__ __forceinline__ ushort f2bf(float f) {
  __hip_bfloat16 h = __float2bfloat16(f);
  return *reinterpret_cast<ushort*>(&h);
}

// ---- pack W [e][K][N] fp32 -> Wp[e][nT=N/128][kt=K/64][row=N%128][c=K%64] bf16,
// ---- with byte-swizzle baked in: ushort pos u holds col c = u ^ ((row&7)<<3).
template <int K, int N>
__global__ void pack_w(const float* __restrict__ in, ushort* __restrict__ outp) {
  __shared__ float t[64][129];
  const int e = blockIdx.z, nT = blockIdx.x, kt = blockIdx.y;
  const float* src = in + (size_t)e * K * N + (size_t)kt * 64 * N + (size_t)nT * 128;
  const int tid = threadIdx.x;
#pragma unroll
  for (int it = 0; it < 8; ++it) {
    int idx = it * 256 + tid;
    int kl = idx >> 5, n4 = idx & 31;
    float4 v = *reinterpret_cast<const float4*>(src + (size_t)kl * N + n4 * 4);
    t[kl][n4 * 4 + 0] = v.x; t[kl][n4 * 4 + 1] = v.y;
    t[kl][n4 * 4 + 2] = v.z; t[kl][n4 * 4 + 3] = v.w;
  }
  __syncthreads();
  const int row = tid >> 1, half = tid & 1;
  const int s = (row & 7) << 3;
  union { ushort us[32]; uint4 q[4]; } u;
#pragma unroll
  for (int k2 = 0; k2 < 32; ++k2) u.us[k2] = f2bf(t[(half * 32 + k2) ^ s][row]);
  ushort* dst = outp + ((size_t)(e * (N / 128) + nT) * (K / 64) + kt) * 8192 + row * 64 + half * 32;
  uint4* d4 = reinterpret_cast<uint4*>(dst);
  d4[0] = u.q[0]; d4[1] = u.q[1]; d4[2] = u.q[2]; d4[3] = u.q[3];
}

// ---------------- router (fused x->bf16 conversion) ----------------
__global__ void router_kernel(const float* __restrict__ x, const float* __restrict__ router,
                              int* __restrict__ cnt, int* __restrict__ list,
                              float* __restrict__ wa, ushort* __restrict__ xb) {
  __shared__ float rl[DM * NE];  // 32 KB
  int tid = threadIdx.x;
  for (int i = tid; i < DM * NE / 4; i += 256)
    reinterpret_cast<float4*>(rl)[i] = reinterpret_cast<const float4*>(router)[i];
  __syncthreads();
  int wave = tid >> 6, lane = tid & 63;
  int tok0 = blockIdx.x * 32 + wave * 8;
  for (int tI = 0; tI < 8; ++tI) {
    int tok = tok0 + tI;
    float acc[NE];
#pragma unroll
    for (int e2 = 0; e2 < NE; ++e2) acc[e2] = 0.f;
    const float4* xr = reinterpret_cast<const float4*>(x + (size_t)tok * DM);
    ushort xo[16];
#pragma unroll
    for (int c = 0; c < 4; ++c) {
      float4 v = xr[lane * 4 + c];
      int d = lane * 16 + c * 4;
      const float* vv = reinterpret_cast<const float*>(&v);
#pragma unroll
      for (int q = 0; q < 4; ++q) {
        float xv = vv[q];
        xo[c * 4 + q] = f2bf(xv);
#pragma unroll
        for (int e2 = 0; e2 < NE; ++e2) acc[e2] += xv * rl[(d + q) * NE + e2];
      }
    }
    *reinterpret_cast<uint4*>(xb + (size_t)tok * DM + lane * 16) =
        *reinterpret_cast<const uint4*>(&xo[0]);
    *reinterpret_cast<uint4*>(xb + (size_t)tok * DM + lane * 16 + 8) =
        *reinterpret_cast<const uint4*>(&xo[8]);
    for (int off = 32; off > 0; off >>= 1) {
#pragma unroll
      for (int e2 = 0; e2 < NE; ++e2) acc[e2] += __shfl_xor(acc[e2], off, 64);
    }
    if (lane == 0) {
      int i0 = 0; float v0 = acc[0];
#pragma unroll
      for (int e2 = 1; e2 < NE; ++e2) { if (acc[e2] > v0) { v0 = acc[e2]; i0 = e2; } }
      int i1 = -1; float v1 = -3.4e38f;
#pragma unroll
      for (int e2 = 0; e2 < NE; ++e2) { if (e2 != i0 && acc[e2] > v1) { v1 = acc[e2]; i1 = e2; } }
      float e1 = expf(v1 - v0);
      float w0 = 1.f / (1.f + e1);
      float w1 = e1 / (1.f + e1);
      int s0 = atomicAdd(&cnt[i0], 1);
      list[i0 * NTOK + s0] = tok * 2;
      wa[tok * 2] = w0;
      int s1 = atomicAdd(&cnt[i1], 1);
      list[i1 * NTOK + s1] = tok * 2 + 1;
      wa[tok * 2 + 1] = w1;
    }
  }
}

// ---------------- tile table: flat tile -> (expert, tTile), BM=128 ----------------
__global__ void build_tiles(const int* __restrict__ cnt, unsigned* __restrict__ table) {
  if (threadIdx.x == 0) {
    int t = 0;
    for (int e = 0; e < NE; ++e) {
      int nt = (cnt[e] + 127) >> 7;
      for (int i = 0; i < nt; ++i) table[t++] = ((unsigned)e << 16) | (unsigned)i;
    }
    for (; t < MAXT; ++t) table[t] = 0xFFFFFFFFu;
  }
}

// ---------------- helpers ----------------
__device__ __forceinline__ void gl_lds16(unsigned long long g, void* s) {
  __builtin_amdgcn_global_load_lds(
      (const __attribute__((address_space(1))) unsigned int*)g,
      (__attribute__((address_space(3))) unsigned int*)s, 16, 0, 0);
}

#define WAITV0() asm volatile("s_waitcnt vmcnt(0)" ::: "memory")

__device__ __forceinline__ void BARRIER() {
  asm volatile("" ::: "memory");
  __builtin_amdgcn_s_barrier();
  asm volatile("" ::: "memory");
}

// ---------------- sparse expert GEMM: R8 machine + packed linear operands ----------------
// 128x128, BK=64, 4 waves, single-buffer 34 KB -> 4 blocks/CU (R8-verified occupancy).
// B (both passes) and A (pass2 = packed H) are CONTIGUOUS 16 KB chunks in staging
// order, swizzle pre-baked -> gl_lds addrs linear, sequential DRAM streams.
// Pass1 ordering: c fastest -> XCD window = 32 tiles x 4 chunks, ~2 experts' panels
// (1 MB) live per L2, each panel fetched ~once. Pass2: nTile=xcd, kc fastest ->
// the 8 XCD readers of an H-slice are adjacent bids (L3 temporal sharing).
template <int PASS>
__launch_bounds__(256, 4)
__global__ void moe_gemm(const ushort* __restrict__ Xb,
                         const ushort* __restrict__ Wp,
                         ushort* __restrict__ Hp,
                         const int* __restrict__ cnt,
                         const int* __restrict__ list,
                         const unsigned* __restrict__ table,
                         const float* __restrict__ wa,
                         float* __restrict__ out) {
  constexpr int NK = (PASS == 1) ? 16 : 32;  // K-steps (pass2: K=4096 split 2)

  const int bid = blockIdx.x;
  const int xcd = bid & 7;
  const int j = bid >> 3;
  int t, nTile, kc;
  if (PASS == 1) { t = j >> 2; nTile = xcd * 4 + (j & 3); kc = 0; }
  else           { t = j >> 1; nTile = xcd; kc = j & 1; }
  unsigned td = table[t];
  if (td == 0xFFFFFFFFu) return;  // uniform exit before any barrier
  const int e = td >> 16;
  const int tTile = td & 0xFFFF;
  const int n = cnt[e];

  __shared__ __attribute__((aligned(16))) char As[16384];
  __shared__ __attribute__((aligned(16))) char Bs[16384];
  __shared__ int aL[128];
  __shared__ unsigned long long pL[128];

  const int tid = threadIdx.x;
  if constexpr (PASS == 1) {
    if (tid < 128) {
      int slot = tTile * 128 + tid;
      int sl = (slot < n) ? slot : (n - 1);  // padding rows duplicate last (H rows discarded later)
      int a = list[e * NTOK + sl];
      pL[tid] = (unsigned long long)(Xb + (size_t)(a >> 1) * DM);
    }
  } else {
    if (tid < 128) {
      int slot = tTile * 128 + tid;
      aL[tid] = (slot < n) ? list[e * NTOK + slot] : -1;
    }
  }
  __syncthreads();

  // B source: linear packed chunks
  const char* Bsrc = (const char*)Wp +
      ((size_t)(e * ((PASS == 1) ? 32 : 8) + nTile) * ((PASS == 1) ? 16 : 64) + kc * 32) * 16384;
  // A source
  const char* Asrc = nullptr;
  unsigned long long sA0[4];
  if constexpr (PASS == 1) {
    const int sr = tid >> 3, sc = (tid & 7) * 16;
#pragma unroll
    for (int jj = 0; jj < 4; ++jj) {
      int row = jj * 32 + sr;
      sA0[jj] = pL[row] + (unsigned)(sc ^ ((row & 7) << 4));  // source-swizzled gather (R8)
    }
  } else {
    Asrc = (const char*)Hp + ((size_t)t * 64 + kc * 32) * 16384;  // packed H, linear
  }

  const int wv = tid >> 6, lane = tid & 63;
  const int r0 = (wv >> 1) * 64, c0 = (wv & 1) * 64;

  f32x4 acc[4][4];
#pragma unroll
  for (int m = 0; m < 4; ++m)
#pragma unroll
    for (int nn = 0; nn < 4; ++nn) acc[m][nn] = (f32x4){0.f, 0.f, 0.f, 0.f};

  for (int kt = 0; kt < NK; ++kt) {
    if constexpr (PASS == 1) {
#pragma unroll
      for (int jj = 0; jj < 4; ++jj)
        gl_lds16(sA0[jj] + (unsigned)kt * 128, As + jj * 4096 + tid * 16);
    } else {
#pragma unroll
      for (int jj = 0; jj < 4; ++jj)
        gl_lds16((unsigned long long)(Asrc + (size_t)kt * 16384 + jj * 4096 + tid * 16),
                 As + jj * 4096 + tid * 16);
    }
#pragma unroll
    for (int jj = 0; jj < 4; ++jj)
      gl_lds16((unsigned long long)(Bsrc + (size_t)kt * 16384 + jj * 4096 + tid * 16),
               Bs + jj * 4096 + tid * 16);
    WAITV0();
    BARRIER();
#pragma unroll
    for (int kk = 0; kk < 2; ++kk) {
      const int kb = kk * 64 + (lane >> 4) * 16;
      bf16x8 af[4], bfr[4];
#pragma unroll
      for (int m = 0; m < 4; ++m) {
        int row = r0 + m * 16 + (lane & 15);
        af[m] = *reinterpret_cast<const bf16x8*>(As + row * 128 + (kb ^ ((row & 7) << 4)));
      }
#pragma unroll
      for (int nn = 0; nn < 4; ++nn) {
        int row = c0 + nn * 16 + (lane & 15);
        bfr[nn] = *reinterpret_cast<const bf16x8*>(Bs + row * 128 + (kb ^ ((row & 7) << 4)));
      }
      __builtin_amdgcn_s_setprio(1);
#pragma unroll
      for (int m = 0; m < 4; ++m)
#pragma unroll
        for (int nn = 0; nn < 4; ++nn)
          acc[m][nn] = __builtin_amdgcn_mfma_f32_16x16x32_bf16(af[m], bfr[nn], acc[m][nn], 0, 0, 0);
      __builtin_amdgcn_s_setprio(0);
    }
    BARRIER();  // WAR: all waves done reading before next stage overwrites
  }

  // epilogue — C/D layout: col = lane&15, row = (lane>>4)*4 + j
#pragma unroll
  for (int m = 0; m < 4; ++m) {
#pragma unroll
    for (int jr = 0; jr < 4; ++jr) {
      int lr = r0 + m * 16 + (lane >> 4) * 4 + jr;
      if constexpr (PASS == 1) {
        // write ALL rows (padding rows carry garbage; pass2 discards via aL<0)
#pragma unroll
        for (int nn = 0; nn < 4; ++nn) {
          int cg = nTile * 128 + c0 + nn * 16 + (lane & 15);
          float v = acc[m][nn][jr];
          size_t us = ((size_t)t * 64 + (cg >> 6)) * 8192 + (size_t)lr * 64 +
                      ((cg & 63) ^ ((lr & 7) << 3));
          Hp[us] = f2bf(v / (1.f + expf(-v)));  // swish, packed-swizzled H
        }
      } else {
        int a = aL[lr];
        if (a < 0) continue;
        float w = wa[a];
        int tok = a >> 1;
        float* orow = out + (size_t)tok * DM + nTile * 128 + c0 + (lane & 15);
#pragma unroll
        for (int nn = 0; nn < 4; ++nn)
          atomicAdd(&orow[nn * 16], w * acc[m][nn][jr]);  // 2 experts x 2 kc, commutative
      }
    }
  }
}

extern "C" void kernel_launch(void* const* d_in, const int* in_sizes, int n_in,
                              void* d_out, int out_size, void* d_ws, size_t ws_size,
                              hipStream_t stream) {
  const float* x = (const float*)d_in[0];
  const float* router = (const float*)d_in[1];
  const float* W1 = (const float*)d_in[2];
  const float* W2 = (const float*)d_in[3];
  float* out = (float*)d_out;
  char* ws = (char*)d_ws;

  // region0 [0, 80 MB): Xb (16 MB) + Wp1 (64 MB) during pass1; Wp2 (64 MB) aliases
  // it afterwards (packed between the passes; stream is serial).
  ushort* Xb  = (ushort*)(ws + 0);
  ushort* Wp1 = (ushort*)(ws + (size_t)16 * 1024 * 1024);
  ushort* Wp2 = (ushort*)(ws + 0);  // alias, used only after pass1
  size_t off = (size_t)80 * 1024 * 1024;
  ushort* Hp = (ushort*)(ws + off); off += (size_t)MAXT * 64 * 16384;  // 142.6 MB packed H
  int* cnt  = (int*)(ws + off); off += 256;
  int* list = (int*)(ws + off); off += (size_t)NE * NTOK * 4;
  float* wa = (float*)(ws + off); off += (size_t)NTOK * 2 * 4;
  unsigned* table = (unsigned*)(ws + off); off += MAXT * 4;

  hipMemsetAsync(out, 0, (size_t)NTOK * DM * sizeof(float), stream);
  hipMemsetAsync(cnt, 0, NE * sizeof(int), stream);

  pack_w<DM, DFF><<<dim3(DFF / 128, DM / 64, NE), 256, 0, stream>>>(W1, Wp1);
  router_kernel<<<NTOK / 32, 256, 0, stream>>>(x, router, cnt, list, wa, Xb);
  build_tiles<<<1, 64, 0, stream>>>(cnt, table);

  moe_gemm<1><<<8 * 4 * MAXT, 256, 0, stream>>>(Xb, Wp1, Hp, cnt, list, table, wa, out);

  pack_w<DFF, DM><<<dim3(DM / 128, DFF / 64, NE), 256, 0, stream>>>(W2, Wp2);

  moe_gemm<2><<<8 * 2 * MAXT, 256, 0, stream>>>(Xb, Wp2, Hp, cnt, list, table, wa, out);
}